// Round 1
// baseline (6436.501 us; speedup 1.0000x reference)
//
#include <hip/hip_runtime.h>
#include <hip/hip_bf16.h>
#include <math.h>

// Problem constants
#define Bz 4
#define Vz 2048
#define Rz 5
#define Az 8
#define RA 40   // R*A

__constant__ float NORM_MEAN_C[30] = {
    -3.7189561e-06f, 0.000286194f, 0.0020740835f, 6.5275993f, -0.0052857199f,
    10.554636f, 0.057773598f, 13.915789f, 0.060970016f, 16.840271f,
    0.0570364f, 19.415283f, 0.044104282f, 21.721455f, 0.11490919f,
    23.64683f, 0.099816084f, 25.365578f, 0.01769533f, 26.861437f,
    0.054662503f, 28.197876f, -0.0024771576f, 29.295244f, 0.039666731f,
    30.319246f, 0.0088442909f, 31.160933f, -0.026727753f, 31.874565f};
__constant__ float NORM_VAR_C[30] = {
    3.3091978e-06f, 0.00016750646f, 0.80988622f, 85135.219f, 1.5621265f,
    222580.2f, 8.812871f, 386912.78f, 10.180468f, 566622.44f,
    9.8600769f, 753158.06f, 7.8372045f, 942701.62f, 30.926426f,
    1117233.0f, 25.045353f, 1285543.9f, 6.3646226f, 1441639.1f,
    12.326629f, 1588653.4f, 6.9686499f, 1714707.9f, 10.755516f,
    1836677.8f, 8.416419f, 1940088.8f, 10.344138f, 2029969.6f};

__device__ __forceinline__ float elu_f(float x) {
    return x > 0.f ? x : expm1f(x);
}

// x0[b,v,c] = (signal - mean[c]) * rsqrt(var[c]); total B*V*30 elements
__global__ void norm_kernel(const float* __restrict__ sig, float* __restrict__ x0) {
    int e = blockIdx.x * 256 + threadIdx.x;
    if (e >= Bz * Vz * 30) return;
    int c = e % 30;
    x0[e] = (sig[e] - NORM_MEAN_C[c]) * rsqrtf(NORM_VAR_C[c]);
}

// W_exp[k][n] = kernel[r, (a-o)&7, t, c], k=(r*8+a)*C+c, n=o*T+t
template <int C, int T>
__global__ void expand_w(const float* __restrict__ kern, float* __restrict__ Wx) {
    constexpr int K = RA * C, N = 8 * T;
    int e = blockIdx.x * 256 + threadIdx.x;
    if (e >= K * N) return;
    int n = e % N;
    int k = e / N;
    int o = n / T, t = n % T;
    int c = k % C;
    int ra = k / C;          // r*8 + a
    int a = ra & 7, r = ra >> 3;
    int asrc = (a - o) & 7;
    Wx[e] = kern[((size_t)((r * 8 + asrc) * T + t)) * C + c];
}

// interp[v, ra, c] = sum_j w[v,ra,j] * x[idx[v,ra,j], c]   (one batch)
template <int C>
__global__ void interp_k(const float* __restrict__ x, const int* __restrict__ idx,
                         const float* __restrict__ w, float* __restrict__ out) {
    int e = blockIdx.x * 256 + threadIdx.x;
    if (e >= Vz * RA * C) return;
    int c = e % C;
    int vra = e / C;
    int base = vra * 3;
    int i0 = idx[base], i1 = idx[base + 1], i2 = idx[base + 2];
    float w0 = w[base], w1 = w[base + 1], w2 = w[base + 2];
    out[e] = w0 * x[(size_t)i0 * C + c] + w1 * x[(size_t)i1 * C + c] + w2 * x[(size_t)i2 * C + c];
}

// Tiled SGEMM: out[m][n] = elu( sum_k A[m][k]*W[k][n] + bias[n%T] )
// M = Vz (2048), BM=BN=128, BK=16, 256 threads, 8x8 micro-tile (2x2 of 4x4)
template <int C, int T>
__global__ __launch_bounds__(256) void conv_gemm(const float* __restrict__ A,
                                                 const float* __restrict__ W,
                                                 const float* __restrict__ bias,
                                                 float* __restrict__ out) {
    constexpr int K = RA * C, N = 8 * T;
    __shared__ float As[16][132];
    __shared__ float Bs[16][132];
    const int tid = threadIdx.x;
    const int tx = tid & 15, ty = tid >> 4;
    const int bm = blockIdx.y * 128, bn = blockIdx.x * 128;
    float acc[2][2][4][4] = {};

    for (int k0 = 0; k0 < K; k0 += 16) {
        {
            const int kl = tid & 15, ml0 = tid >> 4;
#pragma unroll
            for (int p = 0; p < 8; ++p)
                As[kl][ml0 + p * 16] = A[(size_t)(bm + ml0 + p * 16) * K + (k0 + kl)];
            const int nl = tid & 127, kl2 = tid >> 7;
#pragma unroll
            for (int p = 0; p < 8; ++p)
                Bs[kl2 + p * 2][nl] = W[(size_t)(k0 + kl2 + p * 2) * N + (bn + nl)];
        }
        __syncthreads();
#pragma unroll
        for (int kk = 0; kk < 16; ++kk) {
            float4 a0 = *reinterpret_cast<const float4*>(&As[kk][ty * 4]);
            float4 a1 = *reinterpret_cast<const float4*>(&As[kk][64 + ty * 4]);
            float4 b0 = *reinterpret_cast<const float4*>(&Bs[kk][tx * 4]);
            float4 b1 = *reinterpret_cast<const float4*>(&Bs[kk][64 + tx * 4]);
            float av[2][4] = {{a0.x, a0.y, a0.z, a0.w}, {a1.x, a1.y, a1.z, a1.w}};
            float bv[2][4] = {{b0.x, b0.y, b0.z, b0.w}, {b1.x, b1.y, b1.z, b1.w}};
#pragma unroll
            for (int ri = 0; ri < 2; ++ri)
#pragma unroll
                for (int rj = 0; rj < 2; ++rj)
#pragma unroll
                    for (int i = 0; i < 4; ++i)
#pragma unroll
                        for (int j = 0; j < 4; ++j)
                            acc[ri][rj][i][j] += av[ri][i] * bv[rj][j];
        }
        __syncthreads();
    }
#pragma unroll
    for (int ri = 0; ri < 2; ++ri)
#pragma unroll
        for (int rj = 0; rj < 2; ++rj)
#pragma unroll
            for (int i = 0; i < 4; ++i)
#pragma unroll
                for (int j = 0; j < 4; ++j) {
                    int m = bm + ri * 64 + ty * 4 + i;
                    int n = bn + rj * 64 + tx * 4 + j;
                    float v = acc[ri][rj][i][j] + bias[n & (T - 1)];
                    out[(size_t)m * N + n] = elu_f(v);
                }
}

// Angular max pool + BN. One wave per vertex; conv row = [8][T].
template <int T>
__global__ __launch_bounds__(256) void amp_bn(const float* __restrict__ conv,
                                              const float* __restrict__ g,
                                              const float* __restrict__ be,
                                              float* __restrict__ xout) {
    constexpr int N = 8 * T;
    const int wave = threadIdx.x >> 6, lane = threadIdx.x & 63;
    const int v = blockIdx.x * 4 + wave;
    const float* row = conv + (size_t)v * N;
    float best = -1.f;
    int bo = 0;
#pragma unroll
    for (int o = 0; o < 8; ++o) {
        float s = 0.f;
        for (int t = lane; t < T; t += 64) {
            float y = row[o * T + t];
            s += y * y;
        }
#pragma unroll
        for (int off = 32; off; off >>= 1) s += __shfl_xor(s, off);
        if (s > best) { best = s; bo = o; }  // first max wins (matches jnp.argmax)
    }
    const float rsbn = rsqrtf(1.0f + 1e-3f);
    for (int t = lane; t < T; t += 64)
        xout[(size_t)v * T + t] = row[bo * T + t] * g[t] * rsbn + be[t];
}

// Global max pool over vertices, two passes. x: [B][V][256]
__global__ void pool1(const float* __restrict__ x, float* __restrict__ partial) {
    int b = blockIdx.x >> 3, ch = blockIdx.x & 7, t = threadIdx.x;
    float m = -INFINITY;
    for (int i = 0; i < 256; ++i) {
        int v = ch * 256 + i;
        m = fmaxf(m, x[((size_t)b * Vz + v) * 256 + t]);
    }
    partial[(size_t)blockIdx.x * 256 + t] = m;
}
__global__ void pool2(const float* __restrict__ partial, float* __restrict__ pooled) {
    int id = blockIdx.x * 256 + threadIdx.x;  // b*256 + t
    int b = id >> 8, t = id & 255;
    float m = -INFINITY;
    for (int ch = 0; ch < 8; ++ch) m = fmaxf(m, partial[((size_t)b * 8 + ch) * 256 + t]);
    pooled[id] = m;
}

// Small dense layer: out[b,n] = act( bias[n] + sum_k in[b,k]*w[k,n] )
__global__ void mlp(const float* __restrict__ in, const float* __restrict__ w,
                    const float* __restrict__ bias, float* __restrict__ out,
                    int Bv, int Kd, int Nd, int act) {
    int id = blockIdx.x * 256 + threadIdx.x;
    if (id >= Bv * Nd) return;
    int b = id / Nd, n = id % Nd;
    float s = bias[n];
    for (int k = 0; k < Kd; ++k) s += in[(size_t)b * Kd + k] * w[(size_t)k * Nd + n];
    if (act) s = elu_f(s);
    out[id] = s;
}

extern "C" void kernel_launch(void* const* d_in, const int* in_sizes, int n_in,
                              void* d_out, int out_size, void* d_ws, size_t ws_size,
                              hipStream_t stream) {
    const float* signal = (const float*)d_in[0];
    const int* bc_idx = (const int*)d_in[1];
    const float* bc_w = (const float*)d_in[2];
    const float* k0 = (const float*)d_in[3];
    const float* b0 = (const float*)d_in[4];
    const float* g0 = (const float*)d_in[5];
    const float* be0 = (const float*)d_in[6];
    const float* k1 = (const float*)d_in[7];
    const float* b1 = (const float*)d_in[8];
    const float* g1 = (const float*)d_in[9];
    const float* be1 = (const float*)d_in[10];
    const float* k2 = (const float*)d_in[11];
    const float* b2 = (const float*)d_in[12];
    const float* g2 = (const float*)d_in[13];
    const float* be2 = (const float*)d_in[14];
    const float* w1 = (const float*)d_in[15];
    const float* c1 = (const float*)d_in[16];
    const float* w2 = (const float*)d_in[17];
    const float* c2 = (const float*)d_in[18];
    const float* w3 = (const float*)d_in[19];
    const float* c3 = (const float*)d_in[20];
    float* outp = (float*)d_out;

    // Workspace layout (floats). Peak ~112 MB.
    float* ws = (float*)d_ws;
    const size_t X_CAP = (size_t)Bz * Vz * 256;  // 2,097,152
    float* xa = ws;
    float* xb = ws + X_CAP;
    float* interp = ws + 2 * X_CAP;         // cap Vz*RA*128 = 10,485,760
    float* wexp = interp + (size_t)10485760; // cap 5120*2048 = 10,485,760
    float* convb = wexp + (size_t)10485760;  // cap Vz*2048 = 4,194,304
    float* partial = convb + (size_t)4194304; // 8192
    float* pooled = partial + 8192;          // 1024
    float* h1 = pooled + 1024;               // 2048
    float* h2 = h1 + 2048;                   // 1024

    // 1. input normalization
    norm_kernel<<<(Bz * Vz * 30 + 255) / 256, 256, 0, stream>>>(signal, xa);

    // ---- layer 0: C=30, T=128 ----
    expand_w<30, 128><<<(1200 * 1024 + 255) / 256, 256, 0, stream>>>(k0, wexp);
    for (int b = 0; b < Bz; ++b) {
        interp_k<30><<<(Vz * RA * 30 + 255) / 256, 256, 0, stream>>>(
            xa + (size_t)b * Vz * 30, bc_idx + (size_t)b * Vz * RA * 3,
            bc_w + (size_t)b * Vz * RA * 3, interp);
        conv_gemm<30, 128><<<dim3(8, 16), 256, 0, stream>>>(interp, wexp, b0, convb);
        amp_bn<128><<<Vz / 4, 256, 0, stream>>>(convb, g0, be0, xb + (size_t)b * Vz * 128);
    }

    // ---- layer 1: C=128, T=128 ----
    expand_w<128, 128><<<(5120 * 1024 + 255) / 256, 256, 0, stream>>>(k1, wexp);
    for (int b = 0; b < Bz; ++b) {
        interp_k<128><<<(Vz * RA * 128 + 255) / 256, 256, 0, stream>>>(
            xb + (size_t)b * Vz * 128, bc_idx + (size_t)b * Vz * RA * 3,
            bc_w + (size_t)b * Vz * RA * 3, interp);
        conv_gemm<128, 128><<<dim3(8, 16), 256, 0, stream>>>(interp, wexp, b1, convb);
        amp_bn<128><<<Vz / 4, 256, 0, stream>>>(convb, g1, be1, xa + (size_t)b * Vz * 128);
    }

    // ---- layer 2: C=128, T=256 ----
    expand_w<128, 256><<<(5120 * 2048 + 255) / 256, 256, 0, stream>>>(k2, wexp);
    for (int b = 0; b < Bz; ++b) {
        interp_k<128><<<(Vz * RA * 128 + 255) / 256, 256, 0, stream>>>(
            xa + (size_t)b * Vz * 128, bc_idx + (size_t)b * Vz * RA * 3,
            bc_w + (size_t)b * Vz * RA * 3, interp);
        conv_gemm<128, 256><<<dim3(16, 16), 256, 0, stream>>>(interp, wexp, b2, convb);
        amp_bn<256><<<Vz / 4, 256, 0, stream>>>(convb, g2, be2, xb + (size_t)b * Vz * 256);
    }

    // ---- global max pool + MLP head ----
    pool1<<<Bz * 8, 256, 0, stream>>>(xb, partial);
    pool2<<<Bz, 256, 0, stream>>>(partial, pooled);
    mlp<<<(Bz * 512 + 255) / 256, 256, 0, stream>>>(pooled, w1, c1, h1, Bz, 256, 512, 1);
    mlp<<<(Bz * 256 + 255) / 256, 256, 0, stream>>>(h1, w2, c2, h2, Bz, 512, 256, 1);
    mlp<<<1, 256, 0, stream>>>(h2, w3, c3, outp, Bz, 256, 40, 0);
}

// Round 3
// 2447.224 us; speedup vs baseline: 2.6301x; 2.6301x over previous
//
#include <hip/hip_runtime.h>
#include <hip/hip_bf16.h>
#include <math.h>

// Problem constants
#define Bz 4
#define Vz 2048
#define RA 40   // R*A = 5*8

typedef short bf16x8 __attribute__((ext_vector_type(8)));
typedef float f32x4 __attribute__((ext_vector_type(4)));

typedef const void __attribute__((address_space(1))) gvoid_t;
typedef void __attribute__((address_space(3))) svoid_t;

__device__ __forceinline__ void gl_lds16(const void* g, void* l) {
    // async global->LDS, 16B per lane; LDS dest = wave-uniform base + lane*16
    __builtin_amdgcn_global_load_lds((gvoid_t*)g, (svoid_t*)l, 16, 0, 0);
}

// fp32 -> bf16 (RNE) and back, manual to keep types simple
__device__ __forceinline__ unsigned short f2bf(float f) {
    union { float f; unsigned u; } x; x.f = f;
    unsigned r = x.u + 0x7FFF + ((x.u >> 16) & 1);
    return (unsigned short)(r >> 16);
}
__device__ __forceinline__ float bf2f(unsigned short h) {
    union { unsigned u; float f; } x; x.u = ((unsigned)h) << 16;
    return x.f;
}

__constant__ float NORM_MEAN_C[30] = {
    -3.7189561e-06f, 0.000286194f, 0.0020740835f, 6.5275993f, -0.0052857199f,
    10.554636f, 0.057773598f, 13.915789f, 0.060970016f, 16.840271f,
    0.0570364f, 19.415283f, 0.044104282f, 21.721455f, 0.11490919f,
    23.64683f, 0.099816084f, 25.365578f, 0.01769533f, 26.861437f,
    0.054662503f, 28.197876f, -0.0024771576f, 29.295244f, 0.039666731f,
    30.319246f, 0.0088442909f, 31.160933f, -0.026727753f, 31.874565f};
__constant__ float NORM_VAR_C[30] = {
    3.3091978e-06f, 0.00016750646f, 0.80988622f, 85135.219f, 1.5621265f,
    222580.2f, 8.812871f, 386912.78f, 10.180468f, 566622.44f,
    9.8600769f, 753158.06f, 7.8372045f, 942701.62f, 30.926426f,
    1117233.0f, 25.045353f, 1285543.9f, 6.3646226f, 1441639.1f,
    12.326629f, 1588653.4f, 6.9686499f, 1714707.9f, 10.755516f,
    1836677.8f, 8.416419f, 1940088.8f, 10.344138f, 2029969.6f};

__device__ __forceinline__ float elu_f(float x) {
    return x > 0.f ? x : expm1f(x);
}

// x0[b,v,c] = (signal - mean[c]) * rsqrt(var[c])
__global__ void norm_kernel(const float* __restrict__ sig, float* __restrict__ x0) {
    int e = blockIdx.x * 256 + threadIdx.x;
    if (e >= Bz * Vz * 30) return;
    int c = e % 30;
    x0[e] = (sig[e] - NORM_MEAN_C[c]) * rsqrtf(NORM_VAR_C[c]);
}

// Weight expand into split-bf16 plane layout:
// value(n,k) = kernel[r,(a-o)&7,t,c], n=o*T+t, k=(r*8+a)*C+c (pad k>=K -> 0)
// storage: [kb][plane(hi=0,lo=1)][n][32] with kb=k/32, kin=k%32
template <int C, int T, int KP>
__global__ void expand_wt(const float* __restrict__ kern, unsigned short* __restrict__ wt) {
    constexpr int K = RA * C, N = 8 * T;
    int e = blockIdx.x * 256 + threadIdx.x;
    if (e >= N * KP) return;
    int k = e % KP;
    int n = e / KP;
    float v = 0.f;
    if (k < K) {
        int o = n / T, t = n % T;
        int ra = k / C, c = k % C;
        int a = ra & 7, r = ra >> 3;
        int asrc = (a - o) & 7;
        v = kern[((size_t)((r * 8 + asrc) * T + t)) * C + c];
    }
    unsigned short hi = f2bf(v);
    unsigned short lo = f2bf(v - bf2f(hi));
    int kb = k >> 5, kin = k & 31;
    size_t ph = ((size_t)(kb * 2) * N + n) * 32 + kin;
    wt[ph] = hi;
    wt[ph + (size_t)N * 32] = lo;
}

// interp for ONE batch: value(row,k) = sum_j w[row,ra,j]*x[idx[row,ra,j],c], k=ra*C+c
// same split-plane layout, ROWS = Vz
template <int C, int KP>
__global__ void interp_split(const float* __restrict__ x, const int* __restrict__ idx,
                             const float* __restrict__ w, unsigned short* __restrict__ out) {
    constexpr int K = RA * C;
    int e = blockIdx.x * 256 + threadIdx.x;
    if (e >= Vz * KP) return;
    int k = e % KP;
    int row = e / KP;
    float v = 0.f;
    if (k < K) {
        int ra = k / C, c = k % C;
        int base = (row * RA + ra) * 3;
        int i0 = idx[base], i1 = idx[base + 1], i2 = idx[base + 2];
        float w0 = w[base], w1 = w[base + 1], w2 = w[base + 2];
        v = w0 * x[(size_t)i0 * C + c] + w1 * x[(size_t)i1 * C + c] +
            w2 * x[(size_t)i2 * C + c];
    }
    unsigned short hi = f2bf(v);
    unsigned short lo = f2bf(v - bf2f(hi));
    int kb = k >> 5, kin = k & 31;
    size_t ph = ((size_t)(kb * 2) * Vz + row) * 32 + kin;
    out[ph] = hi;
    out[ph + (size_t)Vz * 32] = lo;
}

// Split-bf16 MFMA GEMM: out[m][n] = elu( sum_k A[m][k]*Wt[n][k] + bias[n%T] )
// A ~ Ah+Al, W ~ Bh+Bl; acc += Ah*Bh + Ah*Bl + Al*Bh  (3 MFMAs, ~2^-16 operand eps)
// M = Vz (one batch), 128x128 tile, BK=32, 256 threads (4 waves, 2x2 of 64x64).
template <int K, int T>
__global__ __launch_bounds__(256) void mfma_gemm(const unsigned short* __restrict__ A,
                                                 const unsigned short* __restrict__ Wt,
                                                 const float* __restrict__ bias,
                                                 float* __restrict__ out) {
    constexpr int N = 8 * T;
    constexpr int KB = K / 32;
    constexpr int PSA = Vz * 32;   // plane stride (elements) of A buffer
    constexpr int PSB = N * 32;    // plane stride of Wt buffer
    __shared__ unsigned short Ah[128 * 32], Al[128 * 32];
    __shared__ unsigned short Bh[128 * 32], Bl[128 * 32];
    const int tid = threadIdx.x;
    const int wid = tid >> 6;
    const int lane = tid & 63;
    const int bm = blockIdx.y * 128, bn = blockIdx.x * 128;
    const int wm = (wid & 1) * 64, wn = (wid >> 1) * 64;
    const int r0 = tid >> 2;            // 0..63: row within 64-row half
    const int ki = (tid & 3) * 8;       // k element offset (8 bf16 = 16B)
    const int fr = lane & 15, fq = lane >> 4;
    f32x4 acc[4][4] = {};

    for (int kb = 0; kb < KB; ++kb) {
        const unsigned short* aph = A + (size_t)(kb * 2) * PSA;
        const unsigned short* bph = Wt + (size_t)(kb * 2) * PSB;
        // ---- stage hi/lo tiles (each plane: 128 rows x 32 bf16 = 8KB, 2 issues) ----
        gl_lds16(aph + (size_t)(bm + r0) * 32 + ki,            (char*)Ah + wid * 1024);
        gl_lds16(aph + (size_t)(bm + 64 + r0) * 32 + ki,       (char*)Ah + 4096 + wid * 1024);
        gl_lds16(aph + PSA + (size_t)(bm + r0) * 32 + ki,      (char*)Al + wid * 1024);
        gl_lds16(aph + PSA + (size_t)(bm + 64 + r0) * 32 + ki, (char*)Al + 4096 + wid * 1024);
        gl_lds16(bph + (size_t)(bn + r0) * 32 + ki,            (char*)Bh + wid * 1024);
        gl_lds16(bph + (size_t)(bn + 64 + r0) * 32 + ki,       (char*)Bh + 4096 + wid * 1024);
        gl_lds16(bph + PSB + (size_t)(bn + r0) * 32 + ki,      (char*)Bl + wid * 1024);
        gl_lds16(bph + PSB + (size_t)(bn + 64 + r0) * 32 + ki, (char*)Bl + 4096 + wid * 1024);
        __syncthreads();  // drains vmcnt: tiles visible

        bf16x8 ah[4], al[4], bh4[4], bl4[4];
#pragma unroll
        for (int mi = 0; mi < 4; ++mi) {
            int base = (wm + mi * 16 + fr) * 32 + fq * 8;
            ah[mi] = *(const bf16x8*)&Ah[base];
            al[mi] = *(const bf16x8*)&Al[base];
        }
#pragma unroll
        for (int nj = 0; nj < 4; ++nj) {
            int base = (wn + nj * 16 + fr) * 32 + fq * 8;
            bh4[nj] = *(const bf16x8*)&Bh[base];
            bl4[nj] = *(const bf16x8*)&Bl[base];
        }
#pragma unroll
        for (int mi = 0; mi < 4; ++mi)
#pragma unroll
            for (int nj = 0; nj < 4; ++nj) {
                acc[mi][nj] = __builtin_amdgcn_mfma_f32_16x16x32_bf16(ah[mi], bh4[nj],
                                                                      acc[mi][nj], 0, 0, 0);
                acc[mi][nj] = __builtin_amdgcn_mfma_f32_16x16x32_bf16(ah[mi], bl4[nj],
                                                                      acc[mi][nj], 0, 0, 0);
                acc[mi][nj] = __builtin_amdgcn_mfma_f32_16x16x32_bf16(al[mi], bh4[nj],
                                                                      acc[mi][nj], 0, 0, 0);
            }
        __syncthreads();  // all waves done reading before next overwrite
    }

    // epilogue: C/D layout col=lane&15, row=(lane>>4)*4+r
#pragma unroll
    for (int mi = 0; mi < 4; ++mi)
#pragma unroll
        for (int nj = 0; nj < 4; ++nj)
#pragma unroll
            for (int r = 0; r < 4; ++r) {
                int m = bm + wm + mi * 16 + fq * 4 + r;
                int n = bn + wn + nj * 16 + fr;
                float v = acc[mi][nj][r] + bias[n & (T - 1)];
                out[(size_t)m * N + n] = elu_f(v);
            }
}

// Angular max pool + BN. One wave per vertex; conv row = [8][T].
template <int T>
__global__ __launch_bounds__(256) void amp_bn(const float* __restrict__ conv,
                                              const float* __restrict__ g,
                                              const float* __restrict__ be,
                                              float* __restrict__ xout) {
    constexpr int N = 8 * T;
    const int wave = threadIdx.x >> 6, lane = threadIdx.x & 63;
    const int v = blockIdx.x * 4 + wave;
    const float* row = conv + (size_t)v * N;
    float best = -1.f;
    int bo = 0;
#pragma unroll
    for (int o = 0; o < 8; ++o) {
        float s = 0.f;
        for (int t = lane; t < T; t += 64) {
            float y = row[o * T + t];
            s += y * y;
        }
#pragma unroll
        for (int off = 32; off; off >>= 1) s += __shfl_xor(s, off);
        if (s > best) { best = s; bo = o; }  // first max wins (matches jnp.argmax)
    }
    const float rsbn = rsqrtf(1.0f + 1e-3f);
    for (int t = lane; t < T; t += 64)
        xout[(size_t)v * T + t] = row[bo * T + t] * g[t] * rsbn + be[t];
}

// Global max pool over vertices, two passes. x: [B][V][256]
__global__ void pool1(const float* __restrict__ x, float* __restrict__ partial) {
    int b = blockIdx.x >> 3, ch = blockIdx.x & 7, t = threadIdx.x;
    float m = -INFINITY;
    for (int i = 0; i < 256; ++i) {
        int v = ch * 256 + i;
        m = fmaxf(m, x[((size_t)b * Vz + v) * 256 + t]);
    }
    partial[(size_t)blockIdx.x * 256 + t] = m;
}
__global__ void pool2(const float* __restrict__ partial, float* __restrict__ pooled) {
    int id = blockIdx.x * 256 + threadIdx.x;  // b*256 + t
    int b = id >> 8, t = id & 255;
    float m = -INFINITY;
    for (int ch = 0; ch < 8; ++ch) m = fmaxf(m, partial[((size_t)b * 8 + ch) * 256 + t]);
    pooled[id] = m;
}

// Small dense layer: out[b,n] = act( bias[n] + sum_k in[b,k]*w[k,n] )
__global__ void mlp(const float* __restrict__ in, const float* __restrict__ w,
                    const float* __restrict__ bias, float* __restrict__ out,
                    int Bv, int Kd, int Nd, int act) {
    int id = blockIdx.x * 256 + threadIdx.x;
    if (id >= Bv * Nd) return;
    int b = id / Nd, n = id % Nd;
    float s = bias[n];
    for (int k = 0; k < Kd; ++k) s += in[(size_t)b * Kd + k] * w[(size_t)k * Nd + n];
    if (act) s = elu_f(s);
    out[id] = s;
}

extern "C" void kernel_launch(void* const* d_in, const int* in_sizes, int n_in,
                              void* d_out, int out_size, void* d_ws, size_t ws_size,
                              hipStream_t stream) {
    const float* signal = (const float*)d_in[0];
    const int* bc_idx = (const int*)d_in[1];
    const float* bc_w = (const float*)d_in[2];
    const float* k0 = (const float*)d_in[3];
    const float* b0 = (const float*)d_in[4];
    const float* g0 = (const float*)d_in[5];
    const float* be0 = (const float*)d_in[6];
    const float* k1 = (const float*)d_in[7];
    const float* b1 = (const float*)d_in[8];
    const float* g1 = (const float*)d_in[9];
    const float* be1 = (const float*)d_in[10];
    const float* k2 = (const float*)d_in[11];
    const float* b2 = (const float*)d_in[12];
    const float* g2 = (const float*)d_in[13];
    const float* be2 = (const float*)d_in[14];
    const float* w1 = (const float*)d_in[15];
    const float* c1 = (const float*)d_in[16];
    const float* w2 = (const float*)d_in[17];
    const float* c2 = (const float*)d_in[18];
    const float* w3 = (const float*)d_in[19];
    const float* c3 = (const float*)d_in[20];
    float* outp = (float*)d_out;

    // Workspace layout, total ~117.5 MB (== round-0's proven footprint).
    float* ws = (float*)d_ws;
    float* xa = ws;                                   // 8192*256 f32 = 8.39 MB
    float* xb = xa + (size_t)8192 * 256;              // 8.39 MB
    float* convb = xb + (size_t)8192 * 256;           // 2048*2048 f32 = 16.78 MB
    float* small = convb + (size_t)2048 * 2048;       // 16384 floats
    float* partial = small;                           // 8192
    float* pooled = small + 8192;                     // 1024
    float* h1 = small + 9216;                         // 2048
    float* h2 = small + 11264;                        // 1024
    unsigned short* wt = (unsigned short*)(small + 16384);   // 2048*5120*2 u16 = 41.94 MB
    unsigned short* interp = wt + (size_t)2048 * 5120 * 2;   // 2048*5120*2 u16 = 41.94 MB

    // 1. input normalization
    norm_kernel<<<(Bz * Vz * 30 + 255) / 256, 256, 0, stream>>>(signal, xa);

    // ---- layer 0: C=30, K=1200 (pad 1216), T=128, N=1024 ----
    {
        constexpr int KP = 1216, T = 128, N = 8 * T;
        expand_wt<30, T, KP><<<(N * KP + 255) / 256, 256, 0, stream>>>(k0, wt);
        for (int b = 0; b < Bz; ++b) {
            size_t vo = (size_t)b * Vz;
            interp_split<30, KP><<<(Vz * KP + 255) / 256, 256, 0, stream>>>(
                xa + vo * 30, bc_idx + vo * RA * 3, bc_w + vo * RA * 3, interp);
            mfma_gemm<KP, T><<<dim3(N / 128, 16), 256, 0, stream>>>(interp, wt, b0, convb);
            amp_bn<T><<<Vz / 4, 256, 0, stream>>>(convb, g0, be0, xb + vo * T);
        }
    }
    // ---- layer 1: C=128, K=5120, T=128, N=1024 ----
    {
        constexpr int KP = 5120, T = 128, N = 8 * T;
        expand_wt<128, T, KP><<<(N * KP + 255) / 256, 256, 0, stream>>>(k1, wt);
        for (int b = 0; b < Bz; ++b) {
            size_t vo = (size_t)b * Vz;
            interp_split<128, KP><<<(Vz * KP + 255) / 256, 256, 0, stream>>>(
                xb + vo * 128, bc_idx + vo * RA * 3, bc_w + vo * RA * 3, interp);
            mfma_gemm<KP, T><<<dim3(N / 128, 16), 256, 0, stream>>>(interp, wt, b1, convb);
            amp_bn<T><<<Vz / 4, 256, 0, stream>>>(convb, g1, be1, xa + vo * T);
        }
    }
    // ---- layer 2: C=128, K=5120, T=256, N=2048 ----
    {
        constexpr int KP = 5120, T = 256, N = 8 * T;
        expand_wt<128, T, KP><<<(N * KP + 255) / 256, 256, 0, stream>>>(k2, wt);
        for (int b = 0; b < Bz; ++b) {
            size_t vo = (size_t)b * Vz;
            interp_split<128, KP><<<(Vz * KP + 255) / 256, 256, 0, stream>>>(
                xa + vo * 128, bc_idx + vo * RA * 3, bc_w + vo * RA * 3, interp);
            mfma_gemm<KP, T><<<dim3(N / 128, 16), 256, 0, stream>>>(interp, wt, b2, convb);
            amp_bn<T><<<Vz / 4, 256, 0, stream>>>(convb, g2, be2, xb + vo * 256);
        }
    }

    // ---- global max pool + MLP head ----
    pool1<<<Bz * 8, 256, 0, stream>>>(xb, partial);
    pool2<<<Bz, 256, 0, stream>>>(partial, pooled);
    mlp<<<(Bz * 512 + 255) / 256, 256, 0, stream>>>(pooled, w1, c1, h1, Bz, 256, 512, 1);
    mlp<<<(Bz * 256 + 255) / 256, 256, 0, stream>>>(h1, w2, c2, h2, Bz, 512, 256, 1);
    mlp<<<1, 256, 0, stream>>>(h2, w3, c3, outp, Bz, 256, 40, 0);
}

// Round 4
// 1624.052 us; speedup vs baseline: 3.9632x; 1.5069x over previous
//
#include <hip/hip_runtime.h>
#include <hip/hip_bf16.h>
#include <math.h>

// Problem constants
#define Bz 4
#define Vz 2048
#define RA 40   // R*A = 5*8

typedef short bf16x8 __attribute__((ext_vector_type(8)));
typedef float f32x4 __attribute__((ext_vector_type(4)));

typedef const void __attribute__((address_space(1))) gvoid_t;
typedef void __attribute__((address_space(3))) svoid_t;

__device__ __forceinline__ void gl_lds16(const void* g, void* l) {
    // async global->LDS, 16B per lane; LDS dest = wave-uniform base + lane*16
    __builtin_amdgcn_global_load_lds((gvoid_t*)g, (svoid_t*)l, 16, 0, 0);
}

__device__ __forceinline__ unsigned fasu(float f){ union{float f;unsigned u;}x;x.f=f;return x.u; }
__device__ __forceinline__ float usaf(unsigned u){ union{unsigned u;float f;}x;x.u=u;return x.f; }

// fp32 -> bf16 RNE (for weight split, done once)
__device__ __forceinline__ unsigned short f2bf(float f) {
    unsigned u = fasu(f);
    unsigned r = u + 0x7FFF + ((u >> 16) & 1);
    return (unsigned short)(r >> 16);
}
__device__ __forceinline__ float bf2f(unsigned short h) { return usaf(((unsigned)h) << 16); }

__constant__ float NORM_MEAN_C[30] = {
    -3.7189561e-06f, 0.000286194f, 0.0020740835f, 6.5275993f, -0.0052857199f,
    10.554636f, 0.057773598f, 13.915789f, 0.060970016f, 16.840271f,
    0.0570364f, 19.415283f, 0.044104282f, 21.721455f, 0.11490919f,
    23.64683f, 0.099816084f, 25.365578f, 0.01769533f, 26.861437f,
    0.054662503f, 28.197876f, -0.0024771576f, 29.295244f, 0.039666731f,
    30.319246f, 0.0088442909f, 31.160933f, -0.026727753f, 31.874565f};
__constant__ float NORM_VAR_C[30] = {
    3.3091978e-06f, 0.00016750646f, 0.80988622f, 85135.219f, 1.5621265f,
    222580.2f, 8.812871f, 386912.78f, 10.180468f, 566622.44f,
    9.8600769f, 753158.06f, 7.8372045f, 942701.62f, 30.926426f,
    1117233.0f, 25.045353f, 1285543.9f, 6.3646226f, 1441639.1f,
    12.326629f, 1588653.4f, 6.9686499f, 1714707.9f, 10.755516f,
    1836677.8f, 8.416419f, 1940088.8f, 10.344138f, 2029969.6f};

__device__ __forceinline__ float elu_f(float x) {
    return x > 0.f ? x : expm1f(x);
}

// x0[b,v,c] = (signal - mean[c]) * rsqrt(var[c])
__global__ void norm_kernel(const float* __restrict__ sig, float* __restrict__ x0) {
    int e = blockIdx.x * 256 + threadIdx.x;
    if (e >= Bz * Vz * 30) return;
    int c = e % 30;
    x0[e] = (sig[e] - NORM_MEAN_C[c]) * rsqrtf(NORM_VAR_C[c]);
}

// Weight expand: NO rotation (rotations live in M now). Split-bf16, fragment-linear:
// value(n=t, k) = kernel[ra, t, c] with (ra,c) from k; storage per (kb,plane):
// off = (n>>4)*512 + (kk>>3)*128 + (n&15)*8 + (kk&7)   [u16 elements]
template <int CROW, int T, int KB>
__global__ void expand_wt(const float* __restrict__ kern, unsigned short* __restrict__ wt) {
    int e = blockIdx.x * 256 + threadIdx.x;
    if (e >= KB * T * 32) return;
    int kb = e / (T * 32);
    int rem = e % (T * 32);
    int n = rem >> 5, kk = rem & 31;
    int ra, c;
    if (CROW == 128) { ra = kb >> 2; c = (kb & 3) * 32 + kk; }
    else             { ra = kb;      c = kk; }
    float v = (c < CROW) ? kern[((size_t)(ra * T + n)) * CROW + c] : 0.f;
    unsigned short hi = f2bf(v);
    unsigned short lo = f2bf(v - bf2f(hi));
    size_t off = ((size_t)kb * 2) * T * 32 + (n >> 4) * 512 + (kk >> 3) * 128 + (n & 15) * 8 + (kk & 7);
    wt[off] = hi;
    wt[off + (size_t)T * 32] = lo;
}

// Fused conv GEMM: rows m = b*16384 + v*8 + o (M' = 65536), cols n = t (N' = T).
// A[m][k] = sum_j w[v,rr*8+ag,j] * x[b, idx[v,rr*8+ag,j], c], ag = (a'+o)&7, built
// in-kernel with trunc hi/lo split. 3-MFMA split-bf16 accumulate.
// BM=128 (16 vertices x 8 rotations), BN=128, BK=32, 256 thr (4 waves 2x2 of 64x64).
// FUSE: full-row blocks (T=128) -> elu+AMP+BN epilogue writes xout[vg][T].
// !FUSE: writes elu'd conv out[m][T] for external amp_bn.
template <int CROW, int T, int KB, bool FUSE>
__global__ __launch_bounds__(256) void conv_k(const float* __restrict__ x,
                                              const int* __restrict__ bc_idx,
                                              const float* __restrict__ bc_w,
                                              const unsigned short* __restrict__ wt,
                                              const float* __restrict__ bias,
                                              const float* __restrict__ g,
                                              const float* __restrict__ be,
                                              float* __restrict__ xout) {
    __shared__ unsigned short Ah[4096], Al[4096], Bh[4096], Bl[4096];
    __shared__ float normp[128][2];
    __shared__ int bo[16];
    const int tid = threadIdx.x;
    const int wid = tid >> 6, lane = tid & 63;
    const int fr = lane & 15, fq = lane >> 4;
    const int wm = (wid & 1) * 64, wn = (wid >> 1) * 64;
    const int bn = blockIdx.x * 128;
    const int m0 = blockIdx.y * 128;
    const int b = m0 >> 14;                       // batch
    const float* xb_ = x + (size_t)b * Vz * CROW;
    const int* idxb = bc_idx + (size_t)b * Vz * RA * 3;
    const float* wb = bc_w + (size_t)b * Vz * RA * 3;

    // A-build mapping: 256 threads, 16 elements each
    const int rloc = tid >> 1;                    // row in tile 0..127
    const int chalf = tid & 1;                    // which 16-c half
    const int o = rloc & 7;
    const int vglob_b = ((m0 & 16383) >> 3) + (rloc >> 3);   // vertex within batch
    const int offA = (rloc >> 4) * 512 + (chalf * 2) * 128 + (rloc & 15) * 8;

    f32x4 acc[4][4] = {};

    for (int kb = 0; kb < KB; ++kb) {
        // ---- B staging (async, fragment-linear => LDS order == global order) ----
        const unsigned short* bph = wt + ((size_t)kb * 2) * T * 32 + (size_t)bn * 32;
        const unsigned short* bpl = bph + (size_t)T * 32;
        gl_lds16(bph + tid * 8,        (char*)Bh + wid * 1024);
        gl_lds16(bph + 2048 + tid * 8, (char*)Bh + 4096 + wid * 1024);
        gl_lds16(bpl + tid * 8,        (char*)Bl + wid * 1024);
        gl_lds16(bpl + 2048 + tid * 8, (char*)Bl + 4096 + wid * 1024);

        // ---- A build: gather + interp + trunc-split ----
        int ra, c0;
        if (CROW == 128) { ra = kb >> 2; c0 = (kb & 3) * 32; }
        else             { ra = kb;      c0 = 0; }
        const int ag = ((ra & 7) + o) & 7;
        const int gi = (vglob_b * RA + ((ra >> 3) * 8 + ag)) * 3;
        const int i0 = idxb[gi], i1 = idxb[gi + 1], i2 = idxb[gi + 2];
        const float w0 = wb[gi], w1 = wb[gi + 1], w2 = wb[gi + 2];
        const int cs = c0 + chalf * 16;
        float vv[16];
        if (CROW == 128) {
            const float4* q0 = (const float4*)(xb_ + (size_t)i0 * CROW + cs);
            const float4* q1 = (const float4*)(xb_ + (size_t)i1 * CROW + cs);
            const float4* q2 = (const float4*)(xb_ + (size_t)i2 * CROW + cs);
#pragma unroll
            for (int qq = 0; qq < 4; ++qq) {
                float4 a4 = q0[qq], b4 = q1[qq], c4 = q2[qq];
                vv[qq * 4 + 0] = w0 * a4.x + w1 * b4.x + w2 * c4.x;
                vv[qq * 4 + 1] = w0 * a4.y + w1 * b4.y + w2 * c4.y;
                vv[qq * 4 + 2] = w0 * a4.z + w1 * b4.z + w2 * c4.z;
                vv[qq * 4 + 3] = w0 * a4.w + w1 * b4.w + w2 * c4.w;
            }
        } else {
            const float* q0 = xb_ + (size_t)i0 * CROW;
            const float* q1 = xb_ + (size_t)i1 * CROW;
            const float* q2 = xb_ + (size_t)i2 * CROW;
#pragma unroll
            for (int j = 0; j < 16; ++j) {
                int c = cs + j;
                vv[j] = (c < CROW) ? (w0 * q0[c] + w1 * q1[c] + w2 * q2[c]) : 0.f;
            }
        }
        unsigned hiw[8], low_[8];
#pragma unroll
        for (int p = 0; p < 8; ++p) {
            float v0 = vv[2 * p], v1 = vv[2 * p + 1];
            unsigned u0 = fasu(v0), u1 = fasu(v1);
            unsigned h0 = u0 & 0xFFFF0000u, h1 = u1 & 0xFFFF0000u;
            float l0 = v0 - usaf(h0), l1 = v1 - usaf(h1);
            hiw[p] = (u0 >> 16) | h1;
            low_[p] = (fasu(l0) >> 16) | (fasu(l1) & 0xFFFF0000u);
        }
        uint4 h4a = make_uint4(hiw[0], hiw[1], hiw[2], hiw[3]);
        uint4 h4b = make_uint4(hiw[4], hiw[5], hiw[6], hiw[7]);
        uint4 l4a = make_uint4(low_[0], low_[1], low_[2], low_[3]);
        uint4 l4b = make_uint4(low_[4], low_[5], low_[6], low_[7]);
        *(uint4*)&Ah[offA]       = h4a;
        *(uint4*)&Ah[offA + 128] = h4b;
        *(uint4*)&Al[offA]       = l4a;
        *(uint4*)&Al[offA + 128] = l4b;
        __syncthreads();   // A visible + async B drained

        bf16x8 ah[4], al[4], bh[4], bl[4];
#pragma unroll
        for (int mi = 0; mi < 4; ++mi) {
            int ba = ((wm >> 4) + mi) * 512 + lane * 8;
            ah[mi] = *(const bf16x8*)&Ah[ba];
            al[mi] = *(const bf16x8*)&Al[ba];
        }
#pragma unroll
        for (int nj = 0; nj < 4; ++nj) {
            int bb = ((wn >> 4) + nj) * 512 + lane * 8;
            bh[nj] = *(const bf16x8*)&Bh[bb];
            bl[nj] = *(const bf16x8*)&Bl[bb];
        }
#pragma unroll
        for (int mi = 0; mi < 4; ++mi)
#pragma unroll
            for (int nj = 0; nj < 4; ++nj) {
                acc[mi][nj] = __builtin_amdgcn_mfma_f32_16x16x32_bf16(ah[mi], bh[nj], acc[mi][nj], 0, 0, 0);
                acc[mi][nj] = __builtin_amdgcn_mfma_f32_16x16x32_bf16(ah[mi], bl[nj], acc[mi][nj], 0, 0, 0);
                acc[mi][nj] = __builtin_amdgcn_mfma_f32_16x16x32_bf16(al[mi], bh[nj], acc[mi][nj], 0, 0, 0);
            }
        __syncthreads();   // done reading before next overwrite
    }

    if (FUSE) {
        // elu + bias, per-row squared norms, argmax over 8 rotations, BN, write
        float ss[4][4];
#pragma unroll
        for (int mi = 0; mi < 4; ++mi)
#pragma unroll
            for (int r = 0; r < 4; ++r) ss[mi][r] = 0.f;
#pragma unroll
        for (int mi = 0; mi < 4; ++mi)
#pragma unroll
            for (int nj = 0; nj < 4; ++nj)
#pragma unroll
                for (int r = 0; r < 4; ++r) {
                    float val = elu_f(acc[mi][nj][r] + bias[bn + wn + nj * 16 + fr]);
                    acc[mi][nj][r] = val;
                    ss[mi][r] += val * val;
                }
#pragma unroll
        for (int mi = 0; mi < 4; ++mi)
#pragma unroll
            for (int r = 0; r < 4; ++r) {
                float s = ss[mi][r];
                s += __shfl_xor(s, 1); s += __shfl_xor(s, 2);
                s += __shfl_xor(s, 4); s += __shfl_xor(s, 8);
                if (fr == 0) normp[wm + mi * 16 + fq * 4 + r][wn >> 6] = s;
            }
        __syncthreads();
        if (tid < 16) {
            float best = -1.f; int bsel = 0;
#pragma unroll
            for (int oo = 0; oo < 8; ++oo) {
                float tot = normp[tid * 8 + oo][0] + normp[tid * 8 + oo][1];
                if (tot > best) { best = tot; bsel = oo; }   // first max wins
            }
            bo[tid] = bsel;
        }
        __syncthreads();
        const float rsbn = rsqrtf(1.001f);
#pragma unroll
        for (int mi = 0; mi < 4; ++mi)
#pragma unroll
            for (int r = 0; r < 4; ++r) {
                int row = wm + mi * 16 + fq * 4 + r;
                if ((row & 7) == bo[row >> 3]) {
                    int vg = (m0 >> 3) + (row >> 3);   // global vertex 0..8191
#pragma unroll
                    for (int nj = 0; nj < 4; ++nj) {
                        int t = bn + wn + nj * 16 + fr;
                        xout[(size_t)vg * T + t] = acc[mi][nj][r] * g[t] * rsbn + be[t];
                    }
                }
            }
    } else {
        // plain: write elu'd conv output [m][T]
#pragma unroll
        for (int mi = 0; mi < 4; ++mi)
#pragma unroll
            for (int nj = 0; nj < 4; ++nj)
#pragma unroll
                for (int r = 0; r < 4; ++r) {
                    int mrow = m0 + wm + mi * 16 + fq * 4 + r;
                    int t = bn + wn + nj * 16 + fr;
                    xout[(size_t)mrow * T + t] = elu_f(acc[mi][nj][r] + bias[t]);
                }
    }
}

// Angular max pool + BN for layer 2. conv rows = (v,o): row v*2048 + o*256 + t.
// One wave per vertex, 8192 vertices.
template <int T>
__global__ __launch_bounds__(256) void amp_bn(const float* __restrict__ conv,
                                              const float* __restrict__ g,
                                              const float* __restrict__ be,
                                              float* __restrict__ xout) {
    constexpr int N = 8 * T;
    const int wave = threadIdx.x >> 6, lane = threadIdx.x & 63;
    const int v = blockIdx.x * 4 + wave;
    const float* row = conv + (size_t)v * N;
    float best = -1.f;
    int bsel = 0;
#pragma unroll
    for (int o = 0; o < 8; ++o) {
        float s = 0.f;
        for (int t = lane; t < T; t += 64) {
            float y = row[o * T + t];
            s += y * y;
        }
#pragma unroll
        for (int off = 32; off; off >>= 1) s += __shfl_xor(s, off);
        if (s > best) { best = s; bsel = o; }  // first max wins
    }
    const float rsbn = rsqrtf(1.001f);
    for (int t = lane; t < T; t += 64)
        xout[(size_t)v * T + t] = row[bsel * T + t] * g[t] * rsbn + be[t];
}

// Global max pool over vertices, two passes. x: [B][V][256]
__global__ void pool1(const float* __restrict__ x, float* __restrict__ partial) {
    int b = blockIdx.x >> 3, ch = blockIdx.x & 7, t = threadIdx.x;
    float m = -INFINITY;
    for (int i = 0; i < 256; ++i) {
        int v = ch * 256 + i;
        m = fmaxf(m, x[((size_t)b * Vz + v) * 256 + t]);
    }
    partial[(size_t)blockIdx.x * 256 + t] = m;
}
__global__ void pool2(const float* __restrict__ partial, float* __restrict__ pooled) {
    int id = blockIdx.x * 256 + threadIdx.x;  // b*256 + t
    int b = id >> 8, t = id & 255;
    float m = -INFINITY;
    for (int ch = 0; ch < 8; ++ch) m = fmaxf(m, partial[((size_t)b * 8 + ch) * 256 + t]);
    pooled[id] = m;
}

// Small dense layer
__global__ void mlp(const float* __restrict__ in, const float* __restrict__ w,
                    const float* __restrict__ bias, float* __restrict__ out,
                    int Bv, int Kd, int Nd, int act) {
    int id = blockIdx.x * 256 + threadIdx.x;
    if (id >= Bv * Nd) return;
    int b = id / Nd, n = id % Nd;
    float s = bias[n];
    for (int k = 0; k < Kd; ++k) s += in[(size_t)b * Kd + k] * w[(size_t)k * Nd + n];
    if (act) s = elu_f(s);
    out[id] = s;
}

extern "C" void kernel_launch(void* const* d_in, const int* in_sizes, int n_in,
                              void* d_out, int out_size, void* d_ws, size_t ws_size,
                              hipStream_t stream) {
    const float* signal = (const float*)d_in[0];
    const int* bc_idx = (const int*)d_in[1];
    const float* bc_w = (const float*)d_in[2];
    const float* k0 = (const float*)d_in[3];
    const float* b0 = (const float*)d_in[4];
    const float* g0 = (const float*)d_in[5];
    const float* be0 = (const float*)d_in[6];
    const float* k1 = (const float*)d_in[7];
    const float* b1 = (const float*)d_in[8];
    const float* g1 = (const float*)d_in[9];
    const float* be1 = (const float*)d_in[10];
    const float* k2 = (const float*)d_in[11];
    const float* b2 = (const float*)d_in[12];
    const float* g2 = (const float*)d_in[13];
    const float* be2 = (const float*)d_in[14];
    const float* w1 = (const float*)d_in[15];
    const float* c1 = (const float*)d_in[16];
    const float* w2 = (const float*)d_in[17];
    const float* c2 = (const float*)d_in[18];
    const float* w3 = (const float*)d_in[19];
    const float* c3 = (const float*)d_in[20];
    float* outp = (float*)d_out;

    // Workspace: xa 8.4 + xb 8.4 + convb 67.1 + wt 5.3 MB + small ~= 89 MB
    float* ws = (float*)d_ws;
    float* xa = ws;                                    // [8192][<=256] f32
    float* xb = xa + (size_t)8192 * 256;
    float* convb = xb + (size_t)8192 * 256;            // [65536][256] f32
    float* small = convb + (size_t)65536 * 256;
    float* partial = small;                            // 8192
    float* pooled = small + 8192;                      // 1024
    float* h1 = small + 9216;                          // 2048
    float* h2 = small + 11264;                         // 1024
    unsigned short* wt = (unsigned short*)(small + 16384);  // max 160*2*256*32 u16 = 5.24 MB

    // 1. input normalization -> xa [8192][30]
    norm_kernel<<<(Bz * Vz * 30 + 255) / 256, 256, 0, stream>>>(signal, xa);

    // ---- layer 0: CROW=30 (K'=1280, KB=40), T=128, fused AMP ----
    expand_wt<30, 128, 40><<<(40 * 128 * 32 + 255) / 256, 256, 0, stream>>>(k0, wt);
    conv_k<30, 128, 40, true><<<dim3(1, 512), 256, 0, stream>>>(
        xa, bc_idx, bc_w, wt, b0, g0, be0, xb);

    // ---- layer 1: CROW=128 (K=5120, KB=160), T=128, fused AMP ----
    expand_wt<128, 128, 160><<<(160 * 128 * 32 + 255) / 256, 256, 0, stream>>>(k1, wt);
    conv_k<128, 128, 160, true><<<dim3(1, 512), 256, 0, stream>>>(
        xb, bc_idx, bc_w, wt, b1, g1, be1, xa);

    // ---- layer 2: CROW=128, T=256, unfused (2 col-blocks) + amp_bn ----
    expand_wt<128, 256, 160><<<(160 * 256 * 32 + 255) / 256, 256, 0, stream>>>(k2, wt);
    conv_k<128, 256, 160, false><<<dim3(2, 512), 256, 0, stream>>>(
        xa, bc_idx, bc_w, wt, b2, g2, be2, convb);
    amp_bn<256><<<2048, 256, 0, stream>>>(convb, g2, be2, xb);

    // ---- global max pool + MLP head ----
    pool1<<<Bz * 8, 256, 0, stream>>>(xb, partial);
    pool2<<<Bz, 256, 0, stream>>>(partial, pooled);
    mlp<<<(Bz * 512 + 255) / 256, 256, 0, stream>>>(pooled, w1, c1, h1, Bz, 256, 512, 1);
    mlp<<<(Bz * 256 + 255) / 256, 256, 0, stream>>>(h1, w2, c2, h2, Bz, 512, 256, 1);
    mlp<<<1, 256, 0, stream>>>(h2, w3, c3, outp, Bz, 256, 40, 0);
}

// Round 5
// 1071.157 us; speedup vs baseline: 6.0089x; 1.5162x over previous
//
#include <hip/hip_runtime.h>
#include <hip/hip_bf16.h>
#include <math.h>

// Problem constants
#define Bz 4
#define Vz 2048
#define RA 40   // R*A = 5*8

typedef short bf16x8 __attribute__((ext_vector_type(8)));
typedef float f32x4 __attribute__((ext_vector_type(4)));

typedef const void __attribute__((address_space(1))) gvoid_t;
typedef void __attribute__((address_space(3))) svoid_t;

__device__ __forceinline__ void gl_lds16(const void* g, void* l) {
    // async global->LDS, 16B per lane; LDS dest = wave-uniform base + lane*16
    __builtin_amdgcn_global_load_lds((gvoid_t*)g, (svoid_t*)l, 16, 0, 0);
}

__device__ __forceinline__ unsigned fasu(float f){ union{float f;unsigned u;}x;x.f=f;return x.u; }
__device__ __forceinline__ float usaf(unsigned u){ union{unsigned u;float f;}x;x.u=u;return x.f; }

// fp32 -> bf16 RNE (for weight split, done once)
__device__ __forceinline__ unsigned short f2bf(float f) {
    unsigned u = fasu(f);
    unsigned r = u + 0x7FFF + ((u >> 16) & 1);
    return (unsigned short)(r >> 16);
}
__device__ __forceinline__ float bf2f(unsigned short h) { return usaf(((unsigned)h) << 16); }

__constant__ float NORM_MEAN_C[30] = {
    -3.7189561e-06f, 0.000286194f, 0.0020740835f, 6.5275993f, -0.0052857199f,
    10.554636f, 0.057773598f, 13.915789f, 0.060970016f, 16.840271f,
    0.0570364f, 19.415283f, 0.044104282f, 21.721455f, 0.11490919f,
    23.64683f, 0.099816084f, 25.365578f, 0.01769533f, 26.861437f,
    0.054662503f, 28.197876f, -0.0024771576f, 29.295244f, 0.039666731f,
    30.319246f, 0.0088442909f, 31.160933f, -0.026727753f, 31.874565f};
__constant__ float NORM_VAR_C[30] = {
    3.3091978e-06f, 0.00016750646f, 0.80988622f, 85135.219f, 1.5621265f,
    222580.2f, 8.812871f, 386912.78f, 10.180468f, 566622.44f,
    9.8600769f, 753158.06f, 7.8372045f, 942701.62f, 30.926426f,
    1117233.0f, 25.045353f, 1285543.9f, 6.3646226f, 1441639.1f,
    12.326629f, 1588653.4f, 6.9686499f, 1714707.9f, 10.755516f,
    1836677.8f, 8.416419f, 1940088.8f, 10.344138f, 2029969.6f};

__device__ __forceinline__ float elu_f(float x) {
    return x > 0.f ? x : expm1f(x);
}

// x0[b,v,c] = (signal - mean[c]) * rsqrt(var[c])
__global__ void norm_kernel(const float* __restrict__ sig, float* __restrict__ x0) {
    int e = blockIdx.x * 256 + threadIdx.x;
    if (e >= Bz * Vz * 30) return;
    int c = e % 30;
    x0[e] = (sig[e] - NORM_MEAN_C[c]) * rsqrtf(NORM_VAR_C[c]);
}

// Weight expand (no rotation; rotations live in M). Split-bf16, fragment-linear:
// per (kb,plane): off = (n>>4)*512 + (kk>>3)*128 + (n&15)*8 + (kk&7)
template <int CROW, int T, int KB>
__global__ void expand_wt(const float* __restrict__ kern, unsigned short* __restrict__ wt) {
    int e = blockIdx.x * 256 + threadIdx.x;
    if (e >= KB * T * 32) return;
    int kb = e / (T * 32);
    int rem = e % (T * 32);
    int n = rem >> 5, kk = rem & 31;
    int ra, c;
    if (CROW == 128) { ra = kb >> 2; c = (kb & 3) * 32 + kk; }
    else             { ra = kb;      c = kk; }
    float v = (c < CROW) ? kern[((size_t)(ra * T + n)) * CROW + c] : 0.f;
    unsigned short hi = f2bf(v);
    unsigned short lo = f2bf(v - bf2f(hi));
    size_t off = ((size_t)kb * 2) * T * 32 + (n >> 4) * 512 + (kk >> 3) * 128 + (n & 15) * 8 + (kk & 7);
    wt[off] = hi;
    wt[off + (size_t)T * 32] = lo;
}

// Fused conv GEMM, rotation-hoisted: rows m = b*16384 + v*8 + o (M'=65536), cols n=t.
// K-loop = G groups (r,cblk) x 8 a'-steps. Per group, interp tile I[v16][a8][c32]
// (split hi/lo) is built ONCE; per a'-step the A-fragment is a row-rotation of I
// (folded into ds_read address). B tiles are double-buffered and prefetched one
// step ahead via global_load_lds (landing guaranteed by next barrier's vmcnt drain).
template <int CROW, int T, int KB, bool FUSE>
__global__ __launch_bounds__(256) void conv_k(const float* __restrict__ x,
                                              const int* __restrict__ bc_idx,
                                              const float* __restrict__ bc_w,
                                              const unsigned short* __restrict__ wt,
                                              const float* __restrict__ bias,
                                              const float* __restrict__ g,
                                              const float* __restrict__ be,
                                              float* __restrict__ xout) {
    constexpr int CB = (CROW == 128) ? 4 : 1;   // c-blocks per ra
    constexpr int G = KB / 8;                   // (r,cblk) groups
    __shared__ unsigned short Ih[4096], Il[4096];
    __shared__ unsigned short Bh[2][4096], Bl[2][4096];
    __shared__ float normp[128][2];
    __shared__ int bo[16];
    const int tid = threadIdx.x;
    const int wid = tid >> 6, lane = tid & 63;
    const int fr = lane & 15, fq = lane >> 4;
    const int fro = fr & 7, frv = fr & 8;
    const int wm = (wid & 1) * 64, wn = (wid >> 1) * 64;
    const int bn = blockIdx.x * 128;
    const int m0 = blockIdx.y * 128;
    const int b = m0 >> 14;                       // batch
    const float* xb_ = x + (size_t)b * Vz * CROW;
    const int* idxb = bc_idx + (size_t)b * Vz * RA * 3;
    const float* wb = bc_w + (size_t)b * Vz * RA * 3;

    // I-build mapping: thread -> I row j = tid>>1 (v=j>>3, a=j&7), half chalf
    const int rloc = tid >> 1;
    const int chalf = tid & 1;
    const int aI = rloc & 7;
    const int vglob_b = ((m0 & 16383) >> 3) + (rloc >> 3);
    const int offA = (rloc >> 4) * 512 + chalf * 256 + (rloc & 15) * 8;
    // A-fragment base (lane-const); per a': addr = ibase + mi*512 + rot*8
    const int ibase = (wm >> 4) * 512 + fq * 128 + frv * 8;

    f32x4 acc[4][4] = {};

    // pre-issue B stage for step 0 (kb = 0) into buffer 0
    {
        const unsigned short* bph = wt + (size_t)bn * 32;
        gl_lds16(bph + tid * 8,               (char*)Bh[0] + wid * 1024);
        gl_lds16(bph + 2048 + tid * 8,        (char*)Bh[0] + 4096 + wid * 1024);
        gl_lds16(bph + T * 32 + tid * 8,      (char*)Bl[0] + wid * 1024);
        gl_lds16(bph + T * 32 + 2048 + tid * 8, (char*)Bl[0] + 4096 + wid * 1024);
    }

    for (int gidx = 0; gidx < G; ++gidx) {
        const int r = gidx / CB, cb = gidx % CB;
        // ---- gather + interp + trunc-split into registers (once per group) ----
        const int gi = (vglob_b * RA + (r * 8 + aI)) * 3;
        const int i0 = idxb[gi], i1 = idxb[gi + 1], i2 = idxb[gi + 2];
        const float w0 = wb[gi], w1 = wb[gi + 1], w2 = wb[gi + 2];
        const int cs = cb * 32 + chalf * 16;
        float vv[16];
        if (CROW == 128) {
            const float4* q0 = (const float4*)(xb_ + (size_t)i0 * CROW + cs);
            const float4* q1 = (const float4*)(xb_ + (size_t)i1 * CROW + cs);
            const float4* q2 = (const float4*)(xb_ + (size_t)i2 * CROW + cs);
#pragma unroll
            for (int qq = 0; qq < 4; ++qq) {
                float4 a4 = q0[qq], b4 = q1[qq], c4 = q2[qq];
                vv[qq * 4 + 0] = w0 * a4.x + w1 * b4.x + w2 * c4.x;
                vv[qq * 4 + 1] = w0 * a4.y + w1 * b4.y + w2 * c4.y;
                vv[qq * 4 + 2] = w0 * a4.z + w1 * b4.z + w2 * c4.z;
                vv[qq * 4 + 3] = w0 * a4.w + w1 * b4.w + w2 * c4.w;
            }
        } else {
            const float* q0 = xb_ + (size_t)i0 * CROW;
            const float* q1 = xb_ + (size_t)i1 * CROW;
            const float* q2 = xb_ + (size_t)i2 * CROW;
#pragma unroll
            for (int j = 0; j < 16; ++j) {
                int c = cs + j;
                vv[j] = (c < CROW) ? (w0 * q0[c] + w1 * q1[c] + w2 * q2[c]) : 0.f;
            }
        }
        unsigned hiw[8], low_[8];
#pragma unroll
        for (int p = 0; p < 8; ++p) {
            float v0 = vv[2 * p], v1 = vv[2 * p + 1];
            unsigned u0 = fasu(v0), u1 = fasu(v1);
            unsigned h0 = u0 & 0xFFFF0000u, h1 = u1 & 0xFFFF0000u;
            float l0 = v0 - usaf(h0), l1 = v1 - usaf(h1);
            hiw[p] = (u0 >> 16) | h1;
            low_[p] = (fasu(l0) >> 16) | (fasu(l1) & 0xFFFF0000u);
        }
        __syncthreads();   // prev group's I/B reads done; pending B prefetch landed
        *(uint4*)&Ih[offA]       = make_uint4(hiw[0], hiw[1], hiw[2], hiw[3]);
        *(uint4*)&Ih[offA + 128] = make_uint4(hiw[4], hiw[5], hiw[6], hiw[7]);
        *(uint4*)&Il[offA]       = make_uint4(low_[0], low_[1], low_[2], low_[3]);
        *(uint4*)&Il[offA + 128] = make_uint4(low_[4], low_[5], low_[6], low_[7]);
        __syncthreads();   // I visible (B for a'=0 already landed at prev barrier)

        for (int ap = 0; ap < 8; ++ap) {
            if (ap) __syncthreads();  // B[ap&1] landed; reads of B[(ap+1)&1] done
            // prefetch next step's B into the other buffer
            const int s = gidx * 8 + ap;
            if (s + 1 < G * 8) {
                const int gn = (s + 1) >> 3, an = (s + 1) & 7;
                const int kbn = ((gn / CB) * 8 + an) * CB + (gn % CB);
                const unsigned short* bph = wt + ((size_t)kbn * 2) * T * 32 + (size_t)bn * 32;
                const int pn = (ap + 1) & 1;
                gl_lds16(bph + tid * 8,                 (char*)Bh[pn] + wid * 1024);
                gl_lds16(bph + 2048 + tid * 8,          (char*)Bh[pn] + 4096 + wid * 1024);
                gl_lds16(bph + T * 32 + tid * 8,        (char*)Bl[pn] + wid * 1024);
                gl_lds16(bph + T * 32 + 2048 + tid * 8, (char*)Bl[pn] + 4096 + wid * 1024);
            }
            const int p = ap & 1;
            const int rot = (ap + fro) & 7;
            bf16x8 ah[4], al[4], bh[4], bl[4];
#pragma unroll
            for (int mi = 0; mi < 4; ++mi) {
                int ad = ibase + mi * 512 + rot * 8;
                ah[mi] = *(const bf16x8*)&Ih[ad];
                al[mi] = *(const bf16x8*)&Il[ad];
            }
#pragma unroll
            for (int nj = 0; nj < 4; ++nj) {
                int bb = ((wn >> 4) + nj) * 512 + lane * 8;
                bh[nj] = *(const bf16x8*)&Bh[p][bb];
                bl[nj] = *(const bf16x8*)&Bl[p][bb];
            }
#pragma unroll
            for (int mi = 0; mi < 4; ++mi)
#pragma unroll
                for (int nj = 0; nj < 4; ++nj) {
                    acc[mi][nj] = __builtin_amdgcn_mfma_f32_16x16x32_bf16(ah[mi], bh[nj], acc[mi][nj], 0, 0, 0);
                    acc[mi][nj] = __builtin_amdgcn_mfma_f32_16x16x32_bf16(ah[mi], bl[nj], acc[mi][nj], 0, 0, 0);
                    acc[mi][nj] = __builtin_amdgcn_mfma_f32_16x16x32_bf16(al[mi], bh[nj], acc[mi][nj], 0, 0, 0);
                }
        }
    }

    if (FUSE) {
        // elu + bias, per-row squared norms, argmax over 8 rotations, BN, write
        float ss[4][4];
#pragma unroll
        for (int mi = 0; mi < 4; ++mi)
#pragma unroll
            for (int r = 0; r < 4; ++r) ss[mi][r] = 0.f;
#pragma unroll
        for (int mi = 0; mi < 4; ++mi)
#pragma unroll
            for (int nj = 0; nj < 4; ++nj)
#pragma unroll
                for (int r = 0; r < 4; ++r) {
                    float val = elu_f(acc[mi][nj][r] + bias[bn + wn + nj * 16 + fr]);
                    acc[mi][nj][r] = val;
                    ss[mi][r] += val * val;
                }
        __syncthreads();  // all inner-loop LDS reads done (reuse normp region safely)
#pragma unroll
        for (int mi = 0; mi < 4; ++mi)
#pragma unroll
            for (int r = 0; r < 4; ++r) {
                float s = ss[mi][r];
                s += __shfl_xor(s, 1); s += __shfl_xor(s, 2);
                s += __shfl_xor(s, 4); s += __shfl_xor(s, 8);
                if (fr == 0) normp[wm + mi * 16 + fq * 4 + r][wn >> 6] = s;
            }
        __syncthreads();
        if (tid < 16) {
            float best = -1.f; int bsel = 0;
#pragma unroll
            for (int oo = 0; oo < 8; ++oo) {
                float tot = normp[tid * 8 + oo][0] + normp[tid * 8 + oo][1];
                if (tot > best) { best = tot; bsel = oo; }   // first max wins
            }
            bo[tid] = bsel;
        }
        __syncthreads();
        const float rsbn = rsqrtf(1.001f);
#pragma unroll
        for (int mi = 0; mi < 4; ++mi)
#pragma unroll
            for (int r = 0; r < 4; ++r) {
                int row = wm + mi * 16 + fq * 4 + r;
                if ((row & 7) == bo[row >> 3]) {
                    int vg = (m0 >> 3) + (row >> 3);   // global vertex 0..8191
#pragma unroll
                    for (int nj = 0; nj < 4; ++nj) {
                        int t = bn + wn + nj * 16 + fr;
                        xout[(size_t)vg * T + t] = acc[mi][nj][r] * g[t] * rsbn + be[t];
                    }
                }
            }
    } else {
        // plain: write elu'd conv output [m][T]
#pragma unroll
        for (int mi = 0; mi < 4; ++mi)
#pragma unroll
            for (int nj = 0; nj < 4; ++nj)
#pragma unroll
                for (int r = 0; r < 4; ++r) {
                    int mrow = m0 + wm + mi * 16 + fq * 4 + r;
                    int t = bn + wn + nj * 16 + fr;
                    xout[(size_t)mrow * T + t] = elu_f(acc[mi][nj][r] + bias[t]);
                }
    }
}

// Angular max pool + BN for layer 2. conv rows = (v,o). One wave per vertex.
template <int T>
__global__ __launch_bounds__(256) void amp_bn(const float* __restrict__ conv,
                                              const float* __restrict__ g,
                                              const float* __restrict__ be,
                                              float* __restrict__ xout) {
    constexpr int N = 8 * T;
    const int wave = threadIdx.x >> 6, lane = threadIdx.x & 63;
    const int v = blockIdx.x * 4 + wave;
    const float* row = conv + (size_t)v * N;
    float best = -1.f;
    int bsel = 0;
#pragma unroll
    for (int o = 0; o < 8; ++o) {
        float s = 0.f;
        for (int t = lane; t < T; t += 64) {
            float y = row[o * T + t];
            s += y * y;
        }
#pragma unroll
        for (int off = 32; off; off >>= 1) s += __shfl_xor(s, off);
        if (s > best) { best = s; bsel = o; }  // first max wins
    }
    const float rsbn = rsqrtf(1.001f);
    for (int t = lane; t < T; t += 64)
        xout[(size_t)v * T + t] = row[bsel * T + t] * g[t] * rsbn + be[t];
}

// Global max pool over vertices, two passes. x: [B][V][256]
__global__ void pool1(const float* __restrict__ x, float* __restrict__ partial) {
    int b = blockIdx.x >> 3, ch = blockIdx.x & 7, t = threadIdx.x;
    float m = -INFINITY;
    for (int i = 0; i < 256; ++i) {
        int v = ch * 256 + i;
        m = fmaxf(m, x[((size_t)b * Vz + v) * 256 + t]);
    }
    partial[(size_t)blockIdx.x * 256 + t] = m;
}
__global__ void pool2(const float* __restrict__ partial, float* __restrict__ pooled) {
    int id = blockIdx.x * 256 + threadIdx.x;  // b*256 + t
    int b = id >> 8, t = id & 255;
    float m = -INFINITY;
    for (int ch = 0; ch < 8; ++ch) m = fmaxf(m, partial[((size_t)b * 8 + ch) * 256 + t]);
    pooled[id] = m;
}

// Small dense layer
__global__ void mlp(const float* __restrict__ in, const float* __restrict__ w,
                    const float* __restrict__ bias, float* __restrict__ out,
                    int Bv, int Kd, int Nd, int act) {
    int id = blockIdx.x * 256 + threadIdx.x;
    if (id >= Bv * Nd) return;
    int b = id / Nd, n = id % Nd;
    float s = bias[n];
    for (int k = 0; k < Kd; ++k) s += in[(size_t)b * Kd + k] * w[(size_t)k * Nd + n];
    if (act) s = elu_f(s);
    out[id] = s;
}

extern "C" void kernel_launch(void* const* d_in, const int* in_sizes, int n_in,
                              void* d_out, int out_size, void* d_ws, size_t ws_size,
                              hipStream_t stream) {
    const float* signal = (const float*)d_in[0];
    const int* bc_idx = (const int*)d_in[1];
    const float* bc_w = (const float*)d_in[2];
    const float* k0 = (const float*)d_in[3];
    const float* b0 = (const float*)d_in[4];
    const float* g0 = (const float*)d_in[5];
    const float* be0 = (const float*)d_in[6];
    const float* k1 = (const float*)d_in[7];
    const float* b1 = (const float*)d_in[8];
    const float* g1 = (const float*)d_in[9];
    const float* be1 = (const float*)d_in[10];
    const float* k2 = (const float*)d_in[11];
    const float* b2 = (const float*)d_in[12];
    const float* g2 = (const float*)d_in[13];
    const float* be2 = (const float*)d_in[14];
    const float* w1 = (const float*)d_in[15];
    const float* c1 = (const float*)d_in[16];
    const float* w2 = (const float*)d_in[17];
    const float* c2 = (const float*)d_in[18];
    const float* w3 = (const float*)d_in[19];
    const float* c3 = (const float*)d_in[20];
    float* outp = (float*)d_out;

    // Workspace: xa 8.4 + xb 8.4 + convb 67.1 + wt 5.3 MB + small ~= 89 MB
    float* ws = (float*)d_ws;
    float* xa = ws;                                    // [8192][<=256] f32
    float* xb = xa + (size_t)8192 * 256;
    float* convb = xb + (size_t)8192 * 256;            // [65536][256] f32
    float* small = convb + (size_t)65536 * 256;
    float* partial = small;                            // 8192
    float* pooled = small + 8192;                      // 1024
    float* h1 = small + 9216;                          // 2048
    float* h2 = small + 11264;                         // 1024
    unsigned short* wt = (unsigned short*)(small + 16384);  // max 160*2*256*32 u16 = 5.24 MB

    // 1. input normalization -> xa [8192][30]
    norm_kernel<<<(Bz * Vz * 30 + 255) / 256, 256, 0, stream>>>(signal, xa);

    // ---- layer 0: CROW=30 (K'=1280, KB=40), T=128, fused AMP ----
    expand_wt<30, 128, 40><<<(40 * 128 * 32 + 255) / 256, 256, 0, stream>>>(k0, wt);
    conv_k<30, 128, 40, true><<<dim3(1, 512), 256, 0, stream>>>(
        xa, bc_idx, bc_w, wt, b0, g0, be0, xb);

    // ---- layer 1: CROW=128 (K=5120, KB=160), T=128, fused AMP ----
    expand_wt<128, 128, 160><<<(160 * 128 * 32 + 255) / 256, 256, 0, stream>>>(k1, wt);
    conv_k<128, 128, 160, true><<<dim3(1, 512), 256, 0, stream>>>(
        xb, bc_idx, bc_w, wt, b1, g1, be1, xa);

    // ---- layer 2: CROW=128, T=256, unfused (2 col-blocks) + amp_bn ----
    expand_wt<128, 256, 160><<<(160 * 256 * 32 + 255) / 256, 256, 0, stream>>>(k2, wt);
    conv_k<128, 256, 160, false><<<dim3(2, 512), 256, 0, stream>>>(
        xa, bc_idx, bc_w, wt, b2, g2, be2, convb);
    amp_bn<256><<<2048, 256, 0, stream>>>(convb, g2, be2, xb);

    // ---- global max pool + MLP head ----
    pool1<<<Bz * 8, 256, 0, stream>>>(xb, partial);
    pool2<<<Bz, 256, 0, stream>>>(partial, pooled);
    mlp<<<(Bz * 512 + 255) / 256, 256, 0, stream>>>(pooled, w1, c1, h1, Bz, 256, 512, 1);
    mlp<<<(Bz * 256 + 255) / 256, 256, 0, stream>>>(h1, w2, c2, h2, Bz, 512, 256, 1);
    mlp<<<1, 256, 0, stream>>>(h2, w3, c3, outp, Bz, 256, 40, 0);
}

// Round 6
// 864.867 us; speedup vs baseline: 7.4422x; 1.2385x over previous
//
#include <hip/hip_runtime.h>
#include <hip/hip_bf16.h>
#include <math.h>

// Problem constants
#define Bz 4
#define Vz 2048
#define RA 40   // R*A = 5*8

typedef short bf16x8 __attribute__((ext_vector_type(8)));
typedef float f32x4 __attribute__((ext_vector_type(4)));

__device__ __forceinline__ unsigned fasu(float f){ union{float f;unsigned u;}x;x.f=f;return x.u; }
__device__ __forceinline__ float usaf(unsigned u){ union{unsigned u;float f;}x;x.u=u;return x.f; }

// fp32 -> bf16 RNE (weight split, done once per layer)
__device__ __forceinline__ unsigned short f2bf(float f) {
    unsigned u = fasu(f);
    unsigned r = u + 0x7FFF + ((u >> 16) & 1);
    return (unsigned short)(r >> 16);
}
__device__ __forceinline__ float bf2f(unsigned short h) { return usaf(((unsigned)h) << 16); }

__constant__ float NORM_MEAN_C[30] = {
    -3.7189561e-06f, 0.000286194f, 0.0020740835f, 6.5275993f, -0.0052857199f,
    10.554636f, 0.057773598f, 13.915789f, 0.060970016f, 16.840271f,
    0.0570364f, 19.415283f, 0.044104282f, 21.721455f, 0.11490919f,
    23.64683f, 0.099816084f, 25.365578f, 0.01769533f, 26.861437f,
    0.054662503f, 28.197876f, -0.0024771576f, 29.295244f, 0.039666731f,
    30.319246f, 0.0088442909f, 31.160933f, -0.026727753f, 31.874565f};
__constant__ float NORM_VAR_C[30] = {
    3.3091978e-06f, 0.00016750646f, 0.80988622f, 85135.219f, 1.5621265f,
    222580.2f, 8.812871f, 386912.78f, 10.180468f, 566622.44f,
    9.8600769f, 753158.06f, 7.8372045f, 942701.62f, 30.926426f,
    1117233.0f, 25.045353f, 1285543.9f, 6.3646226f, 1441639.1f,
    12.326629f, 1588653.4f, 6.9686499f, 1714707.9f, 10.755516f,
    1836677.8f, 8.416419f, 1940088.8f, 10.344138f, 2029969.6f};

__device__ __forceinline__ float elu_f(float x) {
    return x > 0.f ? x : expm1f(x);
}

// x0[b,v,c] = (signal - mean[c]) * rsqrt(var[c])
__global__ void norm_kernel(const float* __restrict__ sig, float* __restrict__ x0) {
    int e = blockIdx.x * 256 + threadIdx.x;
    if (e >= Bz * Vz * 30) return;
    int c = e % 30;
    x0[e] = (sig[e] - NORM_MEAN_C[c]) * rsqrtf(NORM_VAR_C[c]);
}

// Weight expand (no rotation; rotations live in M). Split-bf16, fragment-linear:
// per (kb,plane): off = (n>>4)*512 + (kk>>3)*128 + (n&15)*8 + (kk&7)
template <int CROW, int T, int KB>
__global__ void expand_wt(const float* __restrict__ kern, unsigned short* __restrict__ wt) {
    int e = blockIdx.x * 256 + threadIdx.x;
    if (e >= KB * T * 32) return;
    int kb = e / (T * 32);
    int rem = e % (T * 32);
    int n = rem >> 5, kk = rem & 31;
    int ra, c;
    if (CROW == 128) { ra = kb >> 2; c = (kb & 3) * 32 + kk; }
    else             { ra = kb;      c = kk; }
    float v = (c < CROW) ? kern[((size_t)(ra * T + n)) * CROW + c] : 0.f;
    unsigned short hi = f2bf(v);
    unsigned short lo = f2bf(v - bf2f(hi));
    size_t off = ((size_t)kb * 2) * T * 32 + (n >> 4) * 512 + (kk >> 3) * 128 + (n & 15) * 8 + (kk & 7);
    wt[off] = hi;
    wt[off + (size_t)T * 32] = lo;
}

template <int CROW>
__device__ __forceinline__ void build_vv_scalar(float* vv, const float* xb_,
                                                int i0, int i1, int i2,
                                                float w0, float w1, float w2, int cs) {
    const float* q0 = xb_ + (size_t)i0 * CROW;
    const float* q1 = xb_ + (size_t)i1 * CROW;
    const float* q2 = xb_ + (size_t)i2 * CROW;
#pragma unroll
    for (int j = 0; j < 16; ++j) {
        int c = cs + j;
        vv[j] = (c < CROW) ? (w0 * q0[c] + w1 * q1[c] + w2 * q2[c]) : 0.f;
    }
}

// Fused conv GEMM, barrier-light: rows m = b*16384 + v*8 + o (M'=65536), cols n=t.
// K-loop = G groups (r,cblk) x 8 a'-steps. Per group, interp tile I[v16][a8][c32]
// (split hi/lo) built ONCE into a double-buffered LDS tile (1 barrier/group).
// B fragments are loaded global->VGPR directly (fragment-linear layout, coalesced,
// L2-resident) -- no LDS staging, no per-step barriers, compiler emits fine vmcnt.
template <int CROW, int T, int KB, bool FUSE>
__global__ __launch_bounds__(256) void conv_k(const float* __restrict__ x,
                                              const int* __restrict__ bc_idx,
                                              const float* __restrict__ bc_w,
                                              const unsigned short* __restrict__ wt,
                                              const float* __restrict__ bias,
                                              const float* __restrict__ g,
                                              const float* __restrict__ be,
                                              float* __restrict__ xout) {
    constexpr int CB = (CROW == 128) ? 4 : 1;   // c-blocks per ra
    constexpr int G = KB / 8;                   // (r,cblk) groups
    __shared__ unsigned short Ih[2][4096], Il[2][4096];
    __shared__ float normp[128][2];
    __shared__ int bo[16];
    const int tid = threadIdx.x;
    const int wid = tid >> 6, lane = tid & 63;
    const int fr = lane & 15, fq = lane >> 4;
    const int fro = fr & 7, frv = fr & 8;
    const int wm = (wid & 1) * 64, wn = (wid >> 1) * 64;
    const int bn = blockIdx.x * 128;
    const int m0 = blockIdx.y * 128;
    const int b = m0 >> 14;                       // batch
    const float* xb_ = x + (size_t)b * Vz * CROW;
    const int* idxb = bc_idx + (size_t)b * Vz * RA * 3;
    const float* wb = bc_w + (size_t)b * Vz * RA * 3;

    // I-build mapping: thread -> I row j = tid>>1 (v=j>>3, a=j&7), c-half chalf
    const int rloc = tid >> 1;
    const int chalf = tid & 1;
    const int aI = rloc & 7;
    const int vglob_b = ((m0 & 16383) >> 3) + (rloc >> 3);
    const int offA = (rloc >> 4) * 512 + chalf * 256 + (rloc & 15) * 8;
    // A-fragment base (lane-const); per a': addr = ibase + mi*512 + rot*8
    const int ibase = (wm >> 4) * 512 + fq * 128 + frv * 8;
    // B-fragment base n-block
    const int nbase = (bn + wn) >> 4;

    f32x4 acc[4][4] = {};

    auto split_write = [&](const float* vv, int buf) {
        unsigned hiw[8], low_[8];
#pragma unroll
        for (int p = 0; p < 8; ++p) {
            float v0 = vv[2 * p], v1 = vv[2 * p + 1];
            unsigned u0 = fasu(v0), u1 = fasu(v1);
            unsigned h0 = u0 & 0xFFFF0000u, h1 = u1 & 0xFFFF0000u;
            float l0 = v0 - usaf(h0), l1 = v1 - usaf(h1);
            hiw[p] = (u0 >> 16) | h1;
            low_[p] = (fasu(l0) >> 16) | (fasu(l1) & 0xFFFF0000u);
        }
        *(uint4*)&Ih[buf][offA]       = make_uint4(hiw[0], hiw[1], hiw[2], hiw[3]);
        *(uint4*)&Ih[buf][offA + 128] = make_uint4(hiw[4], hiw[5], hiw[6], hiw[7]);
        *(uint4*)&Il[buf][offA]       = make_uint4(low_[0], low_[1], low_[2], low_[3]);
        *(uint4*)&Il[buf][offA + 128] = make_uint4(low_[4], low_[5], low_[6], low_[7]);
    };

    // ---- prologue: build I for group 0; prefetch idx/w for group 1 ----
    int i_n0 = 0, i_n1 = 0, i_n2 = 0; float w_n0 = 0.f, w_n1 = 0.f, w_n2 = 0.f;
    {
        const int gi = (vglob_b * RA + aI) * 3;   // g=0 -> r=0
        int a0 = idxb[gi], a1 = idxb[gi + 1], a2 = idxb[gi + 2];
        float b0_ = wb[gi], b1_ = wb[gi + 1], b2_ = wb[gi + 2];
        float vv[16];
        const int cs0 = chalf * 16;               // g=0 -> cb=0
        if (CROW == 128) {
            const float4* q0 = (const float4*)(xb_ + (size_t)a0 * CROW + cs0);
            const float4* q1 = (const float4*)(xb_ + (size_t)a1 * CROW + cs0);
            const float4* q2 = (const float4*)(xb_ + (size_t)a2 * CROW + cs0);
#pragma unroll
            for (int qq = 0; qq < 4; ++qq) {
                float4 a4 = q0[qq], b4 = q1[qq], c4 = q2[qq];
                vv[qq * 4 + 0] = b0_ * a4.x + b1_ * b4.x + b2_ * c4.x;
                vv[qq * 4 + 1] = b0_ * a4.y + b1_ * b4.y + b2_ * c4.y;
                vv[qq * 4 + 2] = b0_ * a4.z + b1_ * b4.z + b2_ * c4.z;
                vv[qq * 4 + 3] = b0_ * a4.w + b1_ * b4.w + b2_ * c4.w;
            }
        } else {
            build_vv_scalar<CROW>(vv, xb_, a0, a1, a2, b0_, b1_, b2_, cs0);
        }
        split_write(vv, 0);
        if (G > 1) {
            const int rn = 1 / CB;
            const int gi2 = (vglob_b * RA + rn * 8 + aI) * 3;
            i_n0 = idxb[gi2]; i_n1 = idxb[gi2 + 1]; i_n2 = idxb[gi2 + 2];
            w_n0 = wb[gi2];   w_n1 = wb[gi2 + 1];   w_n2 = wb[gi2 + 2];
        }
    }
    __syncthreads();

    for (int gidx = 0; gidx < G; ++gidx) {
        const bool hn = (gidx + 1 < G);
        // save next-group idx/w before the g+2 prefetch overwrites them
        const int ni0 = i_n0, ni1 = i_n1, ni2 = i_n2;
        const float nw0 = w_n0, nw1 = w_n1, nw2 = w_n2;
        const int cs_n = ((gidx + 1) % CB) * 32 + chalf * 16;

        // 1. issue x-gathers for group g+1 (results consumed after the MFMA steps)
        float4 qr0[4], qr1[4], qr2[4];
        if (CROW == 128 && hn) {
            const float4* q0 = (const float4*)(xb_ + (size_t)ni0 * CROW + cs_n);
            const float4* q1 = (const float4*)(xb_ + (size_t)ni1 * CROW + cs_n);
            const float4* q2 = (const float4*)(xb_ + (size_t)ni2 * CROW + cs_n);
#pragma unroll
            for (int qq = 0; qq < 4; ++qq) { qr0[qq] = q0[qq]; qr1[qq] = q1[qq]; qr2[qq] = q2[qq]; }
        }
        // 2. prefetch idx/w for group g+2
        if (gidx + 2 < G) {
            const int rn = (gidx + 2) / CB;
            const int gi = (vglob_b * RA + rn * 8 + aI) * 3;
            i_n0 = idxb[gi]; i_n1 = idxb[gi + 1]; i_n2 = idxb[gi + 2];
            w_n0 = wb[gi];   w_n1 = wb[gi + 1];   w_n2 = wb[gi + 2];
        }

        // 3. 8 MFMA steps on I[g&1]; B fragments straight from global (L2)
        const int r8 = (gidx / CB) * 8;
        const int cbg = gidx % CB;
        const int ibuf = gidx & 1;
#pragma unroll
        for (int ap = 0; ap < 8; ++ap) {
            const int kb = (CROW == 128) ? ((r8 + ap) * 4 + cbg) : (r8 + ap);
            const unsigned short* bb = wt + ((size_t)kb * 2) * (T * 32) +
                                       (size_t)nbase * 512 + lane * 8;
            bf16x8 bh[4], bl[4];
#pragma unroll
            for (int nj = 0; nj < 4; ++nj) {
                bh[nj] = *(const bf16x8*)(bb + nj * 512);
                bl[nj] = *(const bf16x8*)(bb + (size_t)T * 32 + nj * 512);
            }
            const int rot = (ap + fro) & 7;
            bf16x8 ah[4], al[4];
#pragma unroll
            for (int mi = 0; mi < 4; ++mi) {
                const int ad = ibase + mi * 512 + rot * 8;
                ah[mi] = *(const bf16x8*)&Ih[ibuf][ad];
                al[mi] = *(const bf16x8*)&Il[ibuf][ad];
            }
#pragma unroll
            for (int mi = 0; mi < 4; ++mi)
#pragma unroll
                for (int nj = 0; nj < 4; ++nj) {
                    acc[mi][nj] = __builtin_amdgcn_mfma_f32_16x16x32_bf16(ah[mi], bh[nj], acc[mi][nj], 0, 0, 0);
                    acc[mi][nj] = __builtin_amdgcn_mfma_f32_16x16x32_bf16(ah[mi], bl[nj], acc[mi][nj], 0, 0, 0);
                    acc[mi][nj] = __builtin_amdgcn_mfma_f32_16x16x32_bf16(al[mi], bh[nj], acc[mi][nj], 0, 0, 0);
                }
        }

        // 4. build + write I for group g+1 into the other buffer
        if (hn) {
            float vv[16];
            if (CROW == 128) {
#pragma unroll
                for (int qq = 0; qq < 4; ++qq) {
                    float4 a4 = qr0[qq], b4 = qr1[qq], c4 = qr2[qq];
                    vv[qq * 4 + 0] = nw0 * a4.x + nw1 * b4.x + nw2 * c4.x;
                    vv[qq * 4 + 1] = nw0 * a4.y + nw1 * b4.y + nw2 * c4.y;
                    vv[qq * 4 + 2] = nw0 * a4.z + nw1 * b4.z + nw2 * c4.z;
                    vv[qq * 4 + 3] = nw0 * a4.w + nw1 * b4.w + nw2 * c4.w;
                }
            } else {
                build_vv_scalar<CROW>(vv, xb_, ni0, ni1, ni2, nw0, nw1, nw2, cs_n);
            }
            split_write(vv, (gidx + 1) & 1);
        }
        __syncthreads();
    }

    if (FUSE) {
        // elu + bias, per-row squared norms, argmax over 8 rotations, BN, write
        float ss[4][4];
#pragma unroll
        for (int mi = 0; mi < 4; ++mi)
#pragma unroll
            for (int r = 0; r < 4; ++r) ss[mi][r] = 0.f;
#pragma unroll
        for (int mi = 0; mi < 4; ++mi)
#pragma unroll
            for (int nj = 0; nj < 4; ++nj)
#pragma unroll
                for (int r = 0; r < 4; ++r) {
                    float val = elu_f(acc[mi][nj][r] + bias[bn + wn + nj * 16 + fr]);
                    acc[mi][nj][r] = val;
                    ss[mi][r] += val * val;
                }
#pragma unroll
        for (int mi = 0; mi < 4; ++mi)
#pragma unroll
            for (int r = 0; r < 4; ++r) {
                float s = ss[mi][r];
                s += __shfl_xor(s, 1); s += __shfl_xor(s, 2);
                s += __shfl_xor(s, 4); s += __shfl_xor(s, 8);
                if (fr == 0) normp[wm + mi * 16 + fq * 4 + r][wn >> 6] = s;
            }
        __syncthreads();
        if (tid < 16) {
            float best = -1.f; int bsel = 0;
#pragma unroll
            for (int oo = 0; oo < 8; ++oo) {
                float tot = normp[tid * 8 + oo][0] + normp[tid * 8 + oo][1];
                if (tot > best) { best = tot; bsel = oo; }   // first max wins
            }
            bo[tid] = bsel;
        }
        __syncthreads();
        const float rsbn = rsqrtf(1.001f);
#pragma unroll
        for (int mi = 0; mi < 4; ++mi)
#pragma unroll
            for (int r = 0; r < 4; ++r) {
                int row = wm + mi * 16 + fq * 4 + r;
                if ((row & 7) == bo[row >> 3]) {
                    int vg = (m0 >> 3) + (row >> 3);   // global vertex 0..8191
#pragma unroll
                    for (int nj = 0; nj < 4; ++nj) {
                        int t = bn + wn + nj * 16 + fr;
                        xout[(size_t)vg * T + t] = acc[mi][nj][r] * g[t] * rsbn + be[t];
                    }
                }
            }
    } else {
        // plain: write elu'd conv output [m][T]
#pragma unroll
        for (int mi = 0; mi < 4; ++mi)
#pragma unroll
            for (int nj = 0; nj < 4; ++nj)
#pragma unroll
                for (int r = 0; r < 4; ++r) {
                    int mrow = m0 + wm + mi * 16 + fq * 4 + r;
                    int t = bn + wn + nj * 16 + fr;
                    xout[(size_t)mrow * T + t] = elu_f(acc[mi][nj][r] + bias[t]);
                }
    }
}

// Angular max pool + BN for layer 2. conv rows = (v,o). One wave per vertex.
template <int T>
__global__ __launch_bounds__(256) void amp_bn(const float* __restrict__ conv,
                                              const float* __restrict__ g,
                                              const float* __restrict__ be,
                                              float* __restrict__ xout) {
    constexpr int N = 8 * T;
    const int wave = threadIdx.x >> 6, lane = threadIdx.x & 63;
    const int v = blockIdx.x * 4 + wave;
    const float* row = conv + (size_t)v * N;
    float best = -1.f;
    int bsel = 0;
#pragma unroll
    for (int o = 0; o < 8; ++o) {
        float s = 0.f;
        for (int t = lane; t < T; t += 64) {
            float y = row[o * T + t];
            s += y * y;
        }
#pragma unroll
        for (int off = 32; off; off >>= 1) s += __shfl_xor(s, off);
        if (s > best) { best = s; bsel = o; }  // first max wins
    }
    const float rsbn = rsqrtf(1.001f);
    for (int t = lane; t < T; t += 64)
        xout[(size_t)v * T + t] = row[bsel * T + t] * g[t] * rsbn + be[t];
}

// Global max pool stage 1. x: [B][V][256] -> partial [B*8][256]
__global__ void pool1(const float* __restrict__ x, float* __restrict__ partial) {
    int b = blockIdx.x >> 3, ch = blockIdx.x & 7, t = threadIdx.x;
    float m = -INFINITY;
    for (int i = 0; i < 256; ++i) {
        int v = ch * 256 + i;
        m = fmaxf(m, x[((size_t)b * Vz + v) * 256 + t]);
    }
    partial[(size_t)blockIdx.x * 256 + t] = m;
}

// Fused head: finish max-pool + 3-layer MLP. One block per batch.
__global__ __launch_bounds__(256) void head_k(const float* __restrict__ partial,
                                              const float* __restrict__ w1, const float* __restrict__ c1,
                                              const float* __restrict__ w2, const float* __restrict__ c2,
                                              const float* __restrict__ w3, const float* __restrict__ c3,
                                              float* __restrict__ outp) {
    __shared__ float p[256], h1s[512], h2s[256];
    const int b = blockIdx.x, tid = threadIdx.x;
    float m = -INFINITY;
#pragma unroll
    for (int ch = 0; ch < 8; ++ch)
        m = fmaxf(m, partial[((size_t)b * 8 + ch) * 256 + tid]);
    p[tid] = m;
    __syncthreads();
#pragma unroll
    for (int rep = 0; rep < 2; ++rep) {
        int n = rep * 256 + tid;
        float s = c1[n];
        for (int k = 0; k < 256; ++k) s += p[k] * w1[k * 512 + n];
        h1s[n] = elu_f(s);
    }
    __syncthreads();
    {
        float s = c2[tid];
        for (int k = 0; k < 512; ++k) s += h1s[k] * w2[k * 256 + tid];
        h2s[tid] = elu_f(s);
    }
    __syncthreads();
    if (tid < 40) {
        float s = c3[tid];
        for (int k = 0; k < 256; ++k) s += h2s[k] * w3[k * 40 + tid];
        outp[b * 40 + tid] = s;
    }
}

extern "C" void kernel_launch(void* const* d_in, const int* in_sizes, int n_in,
                              void* d_out, int out_size, void* d_ws, size_t ws_size,
                              hipStream_t stream) {
    const float* signal = (const float*)d_in[0];
    const int* bc_idx = (const int*)d_in[1];
    const float* bc_w = (const float*)d_in[2];
    const float* k0 = (const float*)d_in[3];
    const float* b0 = (const float*)d_in[4];
    const float* g0 = (const float*)d_in[5];
    const float* be0 = (const float*)d_in[6];
    const float* k1 = (const float*)d_in[7];
    const float* b1 = (const float*)d_in[8];
    const float* g1 = (const float*)d_in[9];
    const float* be1 = (const float*)d_in[10];
    const float* k2 = (const float*)d_in[11];
    const float* b2 = (const float*)d_in[12];
    const float* g2 = (const float*)d_in[13];
    const float* be2 = (const float*)d_in[14];
    const float* w1 = (const float*)d_in[15];
    const float* c1 = (const float*)d_in[16];
    const float* w2 = (const float*)d_in[17];
    const float* c2 = (const float*)d_in[18];
    const float* w3 = (const float*)d_in[19];
    const float* c3 = (const float*)d_in[20];
    float* outp = (float*)d_out;

    // Workspace: xa 8.4 + xb 8.4 + convb 67.1 + small + wt 5.3 MB ~= 89 MB
    float* ws = (float*)d_ws;
    float* xa = ws;                                    // [8192][<=256] f32
    float* xb = xa + (size_t)8192 * 256;
    float* convb = xb + (size_t)8192 * 256;            // [65536][256] f32
    float* small = convb + (size_t)65536 * 256;
    float* partial = small;                            // 8192
    unsigned short* wt = (unsigned short*)(small + 16384);  // max 160*2*256*32 u16 = 5.24 MB

    // 1. input normalization -> xa [8192][30]
    norm_kernel<<<(Bz * Vz * 30 + 255) / 256, 256, 0, stream>>>(signal, xa);

    // ---- layer 0: CROW=30 (K'=1280, KB=40), T=128, fused AMP ----
    expand_wt<30, 128, 40><<<(40 * 128 * 32 + 255) / 256, 256, 0, stream>>>(k0, wt);
    conv_k<30, 128, 40, true><<<dim3(1, 512), 256, 0, stream>>>(
        xa, bc_idx, bc_w, wt, b0, g0, be0, xb);

    // ---- layer 1: CROW=128 (K=5120, KB=160), T=128, fused AMP ----
    expand_wt<128, 128, 160><<<(160 * 128 * 32 + 255) / 256, 256, 0, stream>>>(k1, wt);
    conv_k<128, 128, 160, true><<<dim3(1, 512), 256, 0, stream>>>(
        xb, bc_idx, bc_w, wt, b1, g1, be1, xa);

    // ---- layer 2: CROW=128, T=256, unfused (2 col-blocks) + amp_bn ----
    expand_wt<128, 256, 160><<<(160 * 256 * 32 + 255) / 256, 256, 0, stream>>>(k2, wt);
    conv_k<128, 256, 160, false><<<dim3(2, 512), 256, 0, stream>>>(
        xa, bc_idx, bc_w, wt, b2, g2, be2, convb);
    amp_bn<256><<<2048, 256, 0, stream>>>(convb, g2, be2, xb);

    // ---- global max pool + fused MLP head ----
    pool1<<<Bz * 8, 256, 0, stream>>>(xb, partial);
    head_k<<<Bz, 256, 0, stream>>>(partial, w1, c1, w2, c2, w3, c3, outp);
}